// Round 13
// baseline (533.764 us; speedup 1.0000x reference)
//
#include <hip/hip_runtime.h>
#include <cstdint>

#define NN 20000
#define TT 256
#define EE 320000
#define GG 64
#define EMBD 768
#define FIND 512

typedef __bf16 bf16x8 __attribute__((ext_vector_type(8)));
typedef float f32x4 __attribute__((ext_vector_type(4)));
typedef unsigned int uint32x4 __attribute__((ext_vector_type(4)));

__device__ __forceinline__ float b2f(unsigned short u) {
  union { unsigned int i; float f; } v; v.i = ((unsigned int)u) << 16; return v.f;
}
__device__ __forceinline__ float b2f_lo(unsigned int u) {
  union { unsigned int i; float f; } v; v.i = u << 16; return v.f;
}
__device__ __forceinline__ float b2f_hi(unsigned int u) {
  union { unsigned int i; float f; } v; v.i = u & 0xFFFF0000u; return v.f;
}
__device__ __forceinline__ unsigned short f2bf(float f) {
  union { float f; unsigned int i; } v; v.f = f;
  unsigned int u = v.i;
  return (unsigned short)((u + 0x7FFFu + ((u >> 16) & 1u)) >> 16);
}
__device__ __forceinline__ unsigned int pack2bf(float lo, float hi) {
  return (unsigned int)f2bf(lo) | ((unsigned int)f2bf(hi) << 16);
}

// async global->LDS, 16B per lane. LDS dest is wave-uniform base + lane*16.
__device__ __forceinline__ void gload_lds16(const void* g, void* l) {
  auto gp = reinterpret_cast<const __attribute__((address_space(1))) char*>(
      reinterpret_cast<uintptr_t>(g));
  auto lp = reinterpret_cast<__attribute__((address_space(3))) char*>(
      (unsigned int)(reinterpret_cast<uintptr_t>(l)));
  __builtin_amdgcn_global_load_lds(gp, lp, 16, 0, 0);
}

// ---------------- weight prep --------------------------------------------
// cwb (f32): [0..423] cw[u*8+c] composed 53-tap; [424..431] zc; [432..439] s0;
// [440..447] o0; [448..463] s2; [464..479] o2;
// [512..1791] KL[t][xi][c] (t<10, xi<16, c<8) boundary-low x-kernel;
// [1792..1871] CL[t][c]; [1920..3199] KH[tt][xi'][c]; [3200..3279] CH[tt][c].
// tb16 (bf16): [0..1023] cwA A-frag table [s][lane][j] (A row=c=l&15,
// k=u=32s+8*(l>>4)+j); [1024..1535] w2 B-frag table [lane][j]
// (B col=k=l&15, kdim=c=8*(l>>4)+j).
__global__ __launch_bounds__(256) void k_wprep(
    const float* __restrict__ w0, const float* __restrict__ w1,
    const float* __restrict__ g0, const float* __restrict__ be0,
    const float* __restrict__ mu0, const float* __restrict__ va0,
    const float* __restrict__ g2, const float* __restrict__ be2,
    const float* __restrict__ mu2, const float* __restrict__ va2,
    const float* __restrict__ w2,
    float* __restrict__ cwb, unsigned short* __restrict__ tb16) {
  const int i = threadIdx.x;
  if (i < 8) {
    float s = g0[i] * rsqrtf(va0[i] + 1e-5f);
    float o = be0[i] - mu0[i] * s;
    float ks = 0.f;
    for (int v = 0; v < 21; ++v) ks += w1[v * 8 + i];
    cwb[424 + i] = o * ks;
    cwb[432 + i] = s;
    cwb[440 + i] = o;
  }
  if (i < 16) {
    float s2 = g2[i] * rsqrtf(va2[i] + 1e-5f);
    cwb[448 + i] = s2;
    cwb[464 + i] = be2[i] - mu2[i] * s2;
  }
  for (int e = i; e < 424; e += 256) {
    int u = e >> 3, c = e & 7;
    float s = g0[c] * rsqrtf(va0[c] + 1e-5f);
    float acc = 0.f;
    int v0 = u - 32; if (v0 < 0) v0 = 0;
    int v1 = u; if (v1 > 20) v1 = 20;
    for (int v = v0; v <= v1; ++v) acc += w1[v * 8 + c] * w0[(u - v) * 8 + c];
    cwb[e] = s * acc;
  }
  __syncthreads();
  // KL: corr_lo[t][c] = CL + sum_xi x[xi]*KL[t][xi][c]
  for (int e = i; e < 1280; e += 256) {
    int t = e >> 7, xi = (e >> 3) & 15, c = e & 7;
    float s = cwb[432 + c];
    float a = 0.f;
    for (int p = t - 10; p <= -1; ++p) {
      int wi = xi - p + 16, v = p - t + 10;
      if (wi >= 0 && wi < 33) a += w0[wi * 8 + c] * w1[v * 8 + c];
    }
    cwb[512 + e] = s * a;
  }
  for (int e = i; e < 80; e += 256) {
    int t = e >> 3, c = e & 7;
    float a = 0.f;
    for (int v = 0; v <= 9 - t; ++v) a += w1[v * 8 + c];
    cwb[1792 + e] = cwb[440 + c] * a;
  }
  // KH: hi side, t = 246+tt, xi = 240+xi'
  for (int e = i; e < 1280; e += 256) {
    int tt = e >> 7, xi = 240 + ((e >> 3) & 15), c = e & 7;
    int t = 246 + tt;
    float s = cwb[432 + c];
    float a = 0.f;
    for (int p = 256; p <= t + 10; ++p) {
      int wi = xi - p + 16, v = p - t + 10;
      if (wi >= 0 && wi < 33) a += w0[wi * 8 + c] * w1[v * 8 + c];
    }
    cwb[1920 + e] = s * a;
  }
  for (int e = i; e < 80; e += 256) {
    int tt = e >> 3, c = e & 7;
    float a = 0.f;
    for (int v = 20 - tt; v <= 20; ++v) a += w1[v * 8 + c];
    cwb[3200 + e] = cwb[440 + c] * a;
  }
  // cwA A-frag table: [s][l][j] -> cw[u][c], zero-padded (u>=53 or c>=8)
  for (int e = i; e < 1024; e += 256) {
    int s = e >> 9, l = (e >> 3) & 63, j = e & 7;
    int c = l & 15, u = 32 * s + 8 * (l >> 4) + j;
    float v = (c < 8 && u < 53) ? cwb[u * 8 + c] : 0.f;
    tb16[e] = f2bf(v);
  }
  // w2 B-frag table: [l][j] -> w2[c][k], zero for c>=8
  for (int e = i; e < 512; e += 256) {
    int l = e >> 3, j = e & 7;
    int c = 8 * (l >> 4) + j, k = l & 15;
    float v = (c < 8) ? w2[c * 16 + k] : 0.f;
    tb16[1024 + e] = f2bf(v);
  }
}

// ---------------- fused conv (MFMA) + init ---------------------------------
// r6 conv (structure asymptote). 1 wave per node; composed 53-tap conv as
// MFMA; bf16 parity copies; boundary corrections via precomputed tables.
// r12 init path: weight transposes TILED through LDS (64x64 tiles, 528
// tile-blocks) — coalesced float4 reads + 32B packed writes (verified:
// conv left top-5; k_gemm FETCH dropped 24->13 MB as the RMW fetches from
// scattered 2B stores disappeared).
__global__ __launch_bounds__(256, 3) void k_conv(
    const float* __restrict__ x,
    unsigned short* __restrict__ out,
    const int* __restrict__ ei, int* __restrict__ deg,
    const float* __restrict__ g1w1, const float* __restrict__ g1w2,
    const float* __restrict__ g2w1, const float* __restrict__ g2w2,
    unsigned short* __restrict__ w1T, unsigned short* __restrict__ w2T,
    unsigned short* __restrict__ w3T, unsigned short* __restrict__ w4T,
    const float* __restrict__ cwb, const unsigned short* __restrict__ tb16) {
  __shared__ __align__(16) float xls[4][344];              // idx = x_t + 28
  __shared__ __align__(16) unsigned short xbf[4][4][360];  // parity copies
  __shared__ __align__(16) float tls[64][65];              // transpose tile
  const int tid = threadIdx.x;

  if (blockIdx.x >= NN / 4) {
    // ---- init path (block-uniform branch) ----
    int b = blockIdx.x - NN / 4;
    if (b < 1250) {                   // edge-count: 1250*256 >= EE
      int e = b * 256 + tid;
      if (e < EE) atomicAdd(&deg[ei[EE + e]], 1);
    } else {                          // tiled weight transposes (528 blocks)
      int b2 = b - 1250;
      const float* src; unsigned short* dst; int KD; int tt;
      if (b2 < 96) { src = g1w1; dst = w1T; KD = 512; tt = b2; }
      else {
        int j = b2 - 96;
        int which = j / 144;          // 0..2
        tt = j - which * 144;
        KD = 768;
        src = which == 0 ? g1w2 : (which == 1 ? g2w1 : g2w2);
        dst = which == 0 ? w2T : (which == 1 ? w3T : w4T);
      }
      int nt = tt % 12, kt = tt / 12;
      int n0 = nt * 64, k0 = kt * 64; // dst rows n0.., dst cols k0..
      int r = tid >> 2, cq = tid & 3;
      // read src 64x64 tile (rows k0+r of 768-col src), coalesced float4
      const float* sp = src + (size_t)(k0 + r) * 768 + n0 + cq * 16;
      #pragma unroll
      for (int j = 0; j < 4; ++j) {
        float4 v = *(const float4*)(sp + 4 * j);
        tls[r][cq * 16 + 4 * j + 0] = v.x;
        tls[r][cq * 16 + 4 * j + 1] = v.y;
        tls[r][cq * 16 + 4 * j + 2] = v.z;
        tls[r][cq * 16 + 4 * j + 3] = v.w;
      }
      __syncthreads();
      // write dst row n0+r, cols k0+cq*16 .. +15 (32B packed bf16)
      unsigned int p0 = pack2bf(tls[cq * 16 + 0][r],  tls[cq * 16 + 1][r]);
      unsigned int p1 = pack2bf(tls[cq * 16 + 2][r],  tls[cq * 16 + 3][r]);
      unsigned int p2 = pack2bf(tls[cq * 16 + 4][r],  tls[cq * 16 + 5][r]);
      unsigned int p3 = pack2bf(tls[cq * 16 + 6][r],  tls[cq * 16 + 7][r]);
      unsigned int p4 = pack2bf(tls[cq * 16 + 8][r],  tls[cq * 16 + 9][r]);
      unsigned int p5 = pack2bf(tls[cq * 16 + 10][r], tls[cq * 16 + 11][r]);
      unsigned int p6 = pack2bf(tls[cq * 16 + 12][r], tls[cq * 16 + 13][r]);
      unsigned int p7 = pack2bf(tls[cq * 16 + 14][r], tls[cq * 16 + 15][r]);
      unsigned short* dp = dst + (size_t)(n0 + r) * KD + k0 + cq * 16;
      uint4 o0; o0.x = p0; o0.y = p1; o0.z = p2; o0.w = p3;
      uint4 o1; o1.x = p4; o1.y = p5; o1.z = p6; o1.w = p7;
      *(uint4*)(dp) = o0;
      *(uint4*)(dp + 8) = o1;
    }
    return;
  }

  // ---- conv path ----
  const int wv = tid >> 6;            // node slot within block
  const int l = tid & 63;
  const int n = blockIdx.x * 4 + wv;
  const int hi = l >> 4, tl = l & 15;

  // stage x (f32) + zero halos: idx [0,28) and [284,344)
  float4 xv4 = *(const float4*)(x + (size_t)n * TT + 4 * l);
  *(float4*)&xls[wv][28 + 4 * l] = xv4;
  float4 z4 = make_float4(0.f, 0.f, 0.f, 0.f);
  if (l < 7) *(float4*)&xls[wv][4 * l] = z4;
  else if (l < 22) *(float4*)&xls[wv][284 + 4 * (l - 7)] = z4;
  __syncthreads();

  // ---- staging phase (between barriers): bf16 parity copies + corr ----
  {
    float4 f0 = *(const float4*)&xls[wv][4 * l];
    float4 f1 = *(const float4*)&xls[wv][4 * l + 4];
    unsigned int b0 = f2bf(f0.x), b1 = f2bf(f0.y), b2 = f2bf(f0.z), b3 = f2bf(f0.w);
    unsigned int b4 = f2bf(f1.x), b5 = f2bf(f1.y), b6 = f2bf(f1.z);
    uint2 w;
    w.x = b0 | (b1 << 16); w.y = b2 | (b3 << 16);
    *(uint2*)&xbf[wv][0][4 * l] = w;
    w.x = b1 | (b2 << 16); w.y = b3 | (b4 << 16);
    *(uint2*)&xbf[wv][1][4 * l] = w;
    w.x = b2 | (b3 << 16); w.y = b4 | (b5 << 16);
    *(uint2*)&xbf[wv][2][4 * l] = w;
    w.x = b3 | (b4 << 16); w.y = b5 | (b6 << 16);
    *(uint2*)&xbf[wv][3][4 * l] = w;
  }
  if (l < 21) {
    float4 f0 = *(const float4*)&xls[wv][256 + 4 * l];
    float4 f1 = *(const float4*)&xls[wv][256 + 4 * l + 4];
    unsigned int b0 = f2bf(f0.x), b1 = f2bf(f0.y), b2 = f2bf(f0.z), b3 = f2bf(f0.w);
    unsigned int b4 = f2bf(f1.x), b5 = f2bf(f1.y), b6 = f2bf(f1.z);
    uint2 w;
    w.x = b0 | (b1 << 16); w.y = b2 | (b3 << 16);
    *(uint2*)&xbf[wv][0][256 + 4 * l] = w;
    w.x = b1 | (b2 << 16); w.y = b3 | (b4 << 16);
    *(uint2*)&xbf[wv][1][256 + 4 * l] = w;
    w.x = b2 | (b3 << 16); w.y = b4 | (b5 << 16);
    *(uint2*)&xbf[wv][2][256 + 4 * l] = w;
    w.x = b3 | (b4 << 16); w.y = b5 | (b6 << 16);
    *(uint2*)&xbf[wv][3][256 + 4 * l] = w;
  }

  // boundary corrections (exact, linear in x[0..15] / x[240..255]);
  // zero for non-boundary lanes, applied at m=0 / m=15 in the loop.
  const float* xp = xls[wv];
  float corrL[4] = {0.f, 0.f, 0.f, 0.f};
  float corrH[4] = {0.f, 0.f, 0.f, 0.f};
  if (hi < 2 && tl < 10) {
    float4 c4 = *(const float4*)&cwb[1792 + tl * 8 + hi * 4];
    corrL[0] = c4.x; corrL[1] = c4.y; corrL[2] = c4.z; corrL[3] = c4.w;
    #pragma unroll
    for (int xi = 0; xi < 16; ++xi) {
      float xv = xp[28 + xi];
      float4 k4 = *(const float4*)&cwb[512 + (tl * 16 + xi) * 8 + hi * 4];
      corrL[0] += xv * k4.x; corrL[1] += xv * k4.y;
      corrL[2] += xv * k4.z; corrL[3] += xv * k4.w;
    }
  }
  if (hi < 2 && tl >= 6) {
    int tt = tl - 6;
    float4 c4 = *(const float4*)&cwb[3200 + tt * 8 + hi * 4];
    corrH[0] = c4.x; corrH[1] = c4.y; corrH[2] = c4.z; corrH[3] = c4.w;
    #pragma unroll
    for (int xi = 0; xi < 16; ++xi) {
      float xv = xp[268 + xi];
      float4 k4 = *(const float4*)&cwb[1920 + (tt * 16 + xi) * 8 + hi * 4];
      corrH[0] += xv * k4.x; corrH[1] += xv * k4.y;
      corrH[2] += xv * k4.z; corrH[3] += xv * k4.w;
    }
  }
  __syncthreads();

  // fragment tables (L1-hot, shared by all waves)
  const bf16x8* frp = (const bf16x8*)tb16;
  bf16x8 cwA0 = frp[l];
  bf16x8 cwA1 = frp[64 + l];
  bf16x8 w2f  = frp[128 + l];
  float4 zc4 = *(const float4*)&cwb[424 + (hi & 1) * 4];  // zc[c], c=(hi&1)*4+r
  float s2k = cwb[448 + tl], o2k = cwb[464 + tl];
  const f32x4 zero4 = {0.f, 0.f, 0.f, 0.f};

  // per-lane parity copy + element base: E0(k) = 16k + tl + 8hi + 2
  const int sl = (tl + 2) & 3;
  const char* cb = (const char*)&xbf[wv][sl][0];
  const int ebase = ((tl + 2) & ~3) + 8 * hi;   // (E0(0) - sl), multiple of 4

  // G(k) = frag at E0(k): 8 bf16 at copy index ebase + 16k — preloaded
#define LDF(kk) ({                                                        \
    uint2 _lo = *(const uint2*)(cb + 2 * (ebase + 16 * (kk)));            \
    uint2 _hi = *(const uint2*)(cb + 2 * (ebase + 16 * (kk)) + 8);        \
    __builtin_bit_cast(bf16x8, (uint32x4){_lo.x, _lo.y, _hi.x, _hi.y});   \
  })
  bf16x8 G[18];
  #pragma unroll
  for (int k = 0; k < 18; ++k) G[k] = LDF(k);
#undef LDF

  unsigned short* outn = out + (size_t)n * FIND;

  #pragma unroll
  for (int m = 0; m < 16; ++m) {
    f32x4 acc = zero4;
    acc = __builtin_amdgcn_mfma_f32_16x16x32_bf16(cwA0, G[m], acc, 0, 0, 0);
    acc = __builtin_amdgcn_mfma_f32_16x16x32_bf16(cwA1, G[m + 2], acc, 0, 0, 0);
    float zf[4];
    #pragma unroll
    for (int r = 0; r < 4; ++r) zf[r] = acc[r] + zc4[r];
    if (m == 0) {
      #pragma unroll
      for (int r = 0; r < 4; ++r) zf[r] -= corrL[r];
    } else if (m == 15) {
      #pragma unroll
      for (int r = 0; r < 4; ++r) zf[r] -= corrH[r];
    }

    // relu + pack to bf16 pairs, 2 shfls for partner half (c 4..7)
    unsigned int q0 = pack2bf(fmaxf(zf[0], 0.f), fmaxf(zf[1], 0.f));
    unsigned int q1 = pack2bf(fmaxf(zf[2], 0.f), fmaxf(zf[3], 0.f));
    unsigned int p0 = __shfl_xor(q0, 16);
    unsigned int p1 = __shfl_xor(q1, 16);
    bf16x8 a2 = __builtin_bit_cast(bf16x8, (uint32x4){q0, q1, p0, p1});
    f32x4 pacc = __builtin_amdgcn_mfma_f32_16x16x32_bf16(a2, w2f, zero4, 0, 0, 0);

    // bn2 + relu + mean-pool over 8 t; D2: row t=(l>>4)*4+r, col k=tl
    float v = 0.f;
    #pragma unroll
    for (int r = 0; r < 4; ++r) v += fmaxf(pacc[r] * s2k + o2k, 0.f);
    v += __shfl_xor(v, 16);
    v *= 0.125f;
    if (hi == 0)      outn[(2 * m) * 16 + tl]     = f2bf(v);
    else if (hi == 2) outn[(2 * m + 1) * 16 + tl] = f2bf(v);
  }
}

// ---------------- scan: register-serial, 20 elems/thread, one block ---------
__global__ __launch_bounds__(1024) void k_scan(const int* __restrict__ deg,
                                               int* __restrict__ row_ptr,
                                               int* __restrict__ cursor) {
  __shared__ int wsums[16];
  const int tid = threadIdx.x, lane = tid & 63, wid = tid >> 6;
  const int base = tid * 20;
  int v[20];
  int s = 0;
  #pragma unroll
  for (int i = 0; i < 20; ++i) {
    int idx = base + i;
    int d = (idx < NN) ? deg[idx] : 0;
    v[i] = s;                // local exclusive prefix
    s += d;
  }
  int inc = s;
  #pragma unroll
  for (int off = 1; off < 64; off <<= 1) {
    int t = __shfl_up(inc, off);
    if (lane >= off) inc += t;
  }
  if (lane == 63) wsums[wid] = inc;
  __syncthreads();
  if (wid == 0) {
    int ws = (lane < 16) ? wsums[lane] : 0;
    #pragma unroll
    for (int off = 1; off < 16; off <<= 1) {
      int t = __shfl_up(ws, off);
      if (lane >= off) ws += t;
    }
    if (lane < 16) wsums[lane] = ws;   // inclusive wave-sum prefix
    if (lane == 15) row_ptr[NN] = ws;  // grand total
  }
  __syncthreads();
  int woff = (wid > 0) ? wsums[wid - 1] : 0;
  int texcl = woff + inc - s;
  #pragma unroll
  for (int i = 0; i < 20; ++i) {
    int idx = base + i;
    if (idx < NN) { int e = texcl + v[i]; row_ptr[idx] = e; cursor[idx] = e; }
  }
}

__global__ void k_scatter(const int* __restrict__ ei, int* __restrict__ cursor,
                          int* __restrict__ csr_src) {
  int e = blockIdx.x * 256 + threadIdx.x;
  if (e < EE) {
    int d = ei[EE + e];
    int pos = atomicAdd(&cursor[d], 1);
    csr_src[pos] = ei[e];
  }
}

// ---------------- aggregation: out[n] = h[n] + sum_{e in(n)} h[src[e]] ------
// r11 form: edge loop unrolled x8; LLC-BW-bound (x8 vs x4 was neutral).
template <int KK>
__global__ __launch_bounds__(256) void k_agg(const unsigned short* __restrict__ h,
                                             const int* __restrict__ rp,
                                             const int* __restrict__ csr,
                                             unsigned short* __restrict__ out) {
  const int node = blockIdx.x * 4 + (threadIdx.x >> 6);
  const int lane = threadIdx.x & 63;
  constexpr int NE = (KK == 512) ? 8 : 12;
  float acc[NE];
  {
    const char* hp = (const char*)(h + (size_t)node * KK);
    uint4 v = *(const uint4*)(hp + lane * 16);
    acc[0] = b2f_lo(v.x); acc[1] = b2f_hi(v.x);
    acc[2] = b2f_lo(v.y); acc[3] = b2f_hi(v.y);
    acc[4] = b2f_lo(v.z); acc[5] = b2f_hi(v.z);
    acc[6] = b2f_lo(v.w); acc[7] = b2f_hi(v.w);
    if (KK == 768) {
      uint2 w = *(const uint2*)(hp + 1024 + lane * 8);
      acc[8] = b2f_lo(w.x); acc[9] = b2f_hi(w.x);
      acc[10] = b2f_lo(w.y); acc[11] = b2f_hi(w.y);
    }
  }
  int s = rp[node], e = rp[node + 1];
  int i = s;
  for (; i + 8 <= e; i += 8) {
    const char* sp[8];
    #pragma unroll
    for (int u = 0; u < 8; ++u)
      sp[u] = (const char*)(h + (size_t)csr[i + u] * KK);
    uint4 v[8];
    #pragma unroll
    for (int u = 0; u < 8; ++u) v[u] = *(const uint4*)(sp[u] + lane * 16);
    uint2 w[8];
    if (KK == 768) {
      #pragma unroll
      for (int u = 0; u < 8; ++u)
        w[u] = *(const uint2*)(sp[u] + 1024 + lane * 8);
    }
    #pragma unroll
    for (int u = 0; u < 8; ++u) {
      acc[0] += b2f_lo(v[u].x); acc[1] += b2f_hi(v[u].x);
      acc[2] += b2f_lo(v[u].y); acc[3] += b2f_hi(v[u].y);
      acc[4] += b2f_lo(v[u].z); acc[5] += b2f_hi(v[u].z);
      acc[6] += b2f_lo(v[u].w); acc[7] += b2f_hi(v[u].w);
      if (KK == 768) {
        acc[8]  += b2f_lo(w[u].x); acc[9]  += b2f_hi(w[u].x);
        acc[10] += b2f_lo(w[u].y); acc[11] += b2f_hi(w[u].y);
      }
    }
  }
  for (; i + 4 <= e; i += 4) {
    const char* sp[4];
    #pragma unroll
    for (int u = 0; u < 4; ++u)
      sp[u] = (const char*)(h + (size_t)csr[i + u] * KK);
    uint4 v[4];
    #pragma unroll
    for (int u = 0; u < 4; ++u) v[u] = *(const uint4*)(sp[u] + lane * 16);
    uint2 w[4];
    if (KK == 768) {
      #pragma unroll
      for (int u = 0; u < 4; ++u)
        w[u] = *(const uint2*)(sp[u] + 1024 + lane * 8);
    }
    #pragma unroll
    for (int u = 0; u < 4; ++u) {
      acc[0] += b2f_lo(v[u].x); acc[1] += b2f_hi(v[u].x);
      acc[2] += b2f_lo(v[u].y); acc[3] += b2f_hi(v[u].y);
      acc[4] += b2f_lo(v[u].z); acc[5] += b2f_hi(v[u].z);
      acc[6] += b2f_lo(v[u].w); acc[7] += b2f_hi(v[u].w);
      if (KK == 768) {
        acc[8]  += b2f_lo(w[u].x); acc[9]  += b2f_hi(w[u].x);
        acc[10] += b2f_lo(w[u].y); acc[11] += b2f_hi(w[u].y);
      }
    }
  }
  for (; i < e; ++i) {
    const char* sp = (const char*)(h + (size_t)csr[i] * KK);
    uint4 v = *(const uint4*)(sp + lane * 16);
    acc[0] += b2f_lo(v.x); acc[1] += b2f_hi(v.x);
    acc[2] += b2f_lo(v.y); acc[3] += b2f_hi(v.y);
    acc[4] += b2f_lo(v.z); acc[5] += b2f_hi(v.z);
    acc[6] += b2f_lo(v.w); acc[7] += b2f_hi(v.w);
    if (KK == 768) {
      uint2 w = *(const uint2*)(sp + 1024 + lane * 8);
      acc[8] += b2f_lo(w.x); acc[9] += b2f_hi(w.x);
      acc[10] += b2f_lo(w.y); acc[11] += b2f_hi(w.y);
    }
  }
  char* op = (char*)(out + (size_t)node * KK);
  uint4 v;
  v.x = pack2bf(acc[0], acc[1]); v.y = pack2bf(acc[2], acc[3]);
  v.z = pack2bf(acc[4], acc[5]); v.w = pack2bf(acc[6], acc[7]);
  *(uint4*)(op + lane * 16) = v;
  if (KK == 768) {
    uint2 w;
    w.x = pack2bf(acc[8], acc[9]); w.y = pack2bf(acc[10], acc[11]);
    *(uint2*)(op + 1024 + lane * 8) = w;
  }
}

// ---------------- GEMM: C(M,Nn) = relu(A(M,K) @ Bt(Nn,K)^T + bias) ----------
// r6 K-loop (measured best at this skinny-K fat-M shape) + r13 epilogue
// THROUGH LDS: r12's pair-packed stores still left 32B-per-row segments
// (half a 64B sector -> WRITE_SIZE stayed 2.0x ideal at 61.5MB) and cost
// +28 VGPR for the shfl chain. Now per mt (4 iters) all 4 waves deposit
// bias+relu'd bf16 into a 32x256 LDS tile (reuses As, 16KB), then the block
// writes 512B-contiguous rows (64B per thread) -> every store a full
// sector, zero write amplification, no shfl.
__global__ __launch_bounds__(256, 2) void k_gemm(const unsigned short* __restrict__ A,
                                                 const unsigned short* __restrict__ Bt,
                                                 const float* __restrict__ bias,
                                                 unsigned short* __restrict__ C,
                                                 int M, int K, int Nn) {
  __shared__ __align__(16) unsigned short As[128 * 64];  // 8 tiles x 128 chunks x 16B
  __shared__ __align__(16) unsigned short Bs[256 * 64];  // 16 tiles x 128 chunks x 16B
  const int id = blockIdx.x;
  const int xg = id & 7;              // xcd slot under round-robin
  const int kk = id >> 3;             // 0..59
  const int ntile = kk % 3;
  const int m_tile = (kk / 3) * 8 + xg;   // 0..159
  if (m_tile >= 157) return;
  const int m0 = m_tile * 128;
  const int n0 = ntile * 256;

  const int tid = threadIdx.x;
  const int wave = tid >> 6, lane = tid & 63;
  const int wr = wave & 1, wc = wave >> 1;

  f32x4 zero = {0.f, 0.f, 0.f, 0.f};
  f32x4 acc[4][8];
  #pragma unroll
  for (int mt = 0; mt < 4; ++mt)
    #pragma unroll
    for (int nt = 0; nt < 8; ++nt) acc[mt][nt] = zero;

  for (int k0 = 0; k0 < K; k0 += 64) {
    __syncthreads();
    #pragma unroll
    for (int j = 0; j < 4; ++j) {
      int chunk = j * 256 + tid;                 // 0..1023 (A: 8 tiles)
      int tile = chunk >> 7, c = chunk & 127;
      int row = tile * 16 + (c & 15);
      int koff = (c >> 4) * 8;
      int gm = m0 + row; if (gm >= M) gm = 0;    // clamp: data unused
      gload_lds16(A + (size_t)gm * K + k0 + koff, (char*)As + chunk * 16);
    }
    #pragma unroll
    for (int j = 0; j < 8; ++j) {
      int chunk = j * 256 + tid;                 // 0..2047 (B: 16 tiles)
      int tile = chunk >> 7, c = chunk & 127;
      int row = tile * 16 + (c & 15);
      int koff = (c >> 4) * 8;
      gload_lds16(Bt + (size_t)(n0 + row) * K + k0 + koff, (char*)Bs + chunk * 16);
    }
    __syncthreads();
    #pragma unroll
    for (int s = 0; s < 2; ++s) {
      bf16x8 af[4], bfr[8];
      #pragma unroll
      for (int mt = 0; mt < 4; ++mt)
        af[mt] = *(const bf16x8*)((const char*)As +
                                  (((wr * 4 + mt) * 128 + s * 64 + lane) * 16));
      #pragma unroll
      for (int nt = 0; nt < 8; ++nt)
        bfr[nt] = *(const bf16x8*)((const char*)Bs +
                                   (((wc * 8 + nt) * 128 + s * 64 + lane) * 16));
      #pragma unroll
      for (int mt = 0; mt < 4; ++mt)
        #pragma unroll
        for (int nt = 0; nt < 8; ++nt)
          acc[mt][nt] = __builtin_amdgcn_mfma_f32_16x16x32_bf16(af[mt], bfr[nt], acc[mt][nt], 0, 0, 0);
    }
  }

  // ---- epilogue through LDS (32x256 bf16 tile per mt, reuses As) ----
  const int q = lane >> 4, ccol = lane & 15;
  unsigned short* els = &As[0];       // 32*256 u16 = 16 KB
  #pragma unroll
  for (int mt = 0; mt < 4; ++mt) {
    __syncthreads();  // K-loop reads (mt=0) / prior mt's LDS reads done
    #pragma unroll
    for (int nt = 0; nt < 8; ++nt) {
      int n = n0 + wc * 128 + nt * 16 + ccol;
      float bv = bias[n];
      #pragma unroll
      for (int r = 0; r < 4; ++r) {
        float v = acc[mt][nt][r] + bv;
        v = v > 0.f ? v : 0.f;
        els[(wr * 16 + q * 4 + r) * 256 + wc * 128 + nt * 16 + ccol] = f2bf(v);
      }
    }
    __syncthreads();
    // 32 rows x 512B; 8 threads/row, 64B each — full-sector coalesced
    int rl = tid >> 3, seg = tid & 7;
    int grow = m0 + (rl >> 4) * 64 + mt * 16 + (rl & 15);
    if (grow < M) {
      const uint4* lp = (const uint4*)&els[rl * 256 + seg * 32];
      uint4 v0 = lp[0], v1 = lp[1], v2 = lp[2], v3 = lp[3];
      uint4* gp = (uint4*)&C[(size_t)grow * Nn + n0 + seg * 32];
      gp[0] = v0; gp[1] = v1; gp[2] = v2; gp[3] = v3;
    }
  }
}

// ---------------- pool phase 1: per-graph sums (grid-wide, sorted batch) ----
// 32 nodes/block (625 blocks).
__global__ __launch_bounds__(256) void k_pool1(const unsigned short* __restrict__ h,
                                               const int* __restrict__ batch,
                                               float* __restrict__ sums,
                                               int* __restrict__ cnt) {
  const int tid = threadIdx.x;
  const int n0 = blockIdx.x * 32;
  const int n1 = min(n0 + 32, NN);
  int curg = batch[n0];
  float a0 = 0.f, a1 = 0.f, a2 = 0.f;
  int c = 0;
  for (int n = n0; n < n1; ++n) {
    int g = batch[n];  // uniform across block
    if (g != curg) {
      atomicAdd(&sums[curg * EMBD + tid], a0);
      atomicAdd(&sums[curg * EMBD + tid + 256], a1);
      atomicAdd(&sums[curg * EMBD + tid + 512], a2);
      if (tid == 0) atomicAdd(&cnt[curg], c);
      a0 = a1 = a2 = 0.f; c = 0; curg = g;
    }
    const unsigned short* hp = h + (size_t)n * EMBD;
    a0 += b2f(hp[tid]); a1 += b2f(hp[tid + 256]); a2 += b2f(hp[tid + 512]);
    ++c;
  }
  atomicAdd(&sums[curg * EMBD + tid], a0);
  atomicAdd(&sums[curg * EMBD + tid + 256], a1);
  atomicAdd(&sums[curg * EMBD + tid + 512], a2);
  if (tid == 0) atomicAdd(&cnt[curg], c);
}

// ---------------- pool phase 2: dense 768->4 + log_softmax ------------------
__global__ __launch_bounds__(64) void k_pool2(const float* __restrict__ sums,
                                              const int* __restrict__ cnt,
                                              const float* __restrict__ dw,
                                              const float* __restrict__ db,
                                              float* __restrict__ outp) {
  int g = blockIdx.x, lane = threadIdx.x;
  float inv = 1.f / fmaxf((float)cnt[g], 1.f);
  float po[4] = {0.f, 0.f, 0.f, 0.f};
  #pragma unroll
  for (int i = 0; i < 12; ++i) {
    int f = lane + i * 64;
    float pv = sums[g * EMBD + f] * inv;
    #pragma unroll
    for (int o = 0; o < 4; ++o) po[o] += pv * dw[f * 4 + o];
  }
  #pragma unroll
  for (int o = 0; o < 4; ++o) {
    #pragma unroll
    for (int s = 1; s < 64; s <<= 1) po[o] += __shfl_xor(po[o], s);
  }
  if (lane == 0) {
    float l[4], m = -1e30f;
    #pragma unroll
    for (int o = 0; o < 4; ++o) { l[o] = po[o] + db[o]; m = fmaxf(m, l[o]); }
    float sum = 0.f;
    #pragma unroll
    for (int o = 0; o < 4; ++o) sum += expf(l[o] - m);
    float lse = m + logf(sum);
    #pragma unroll
    for (int o = 0; o < 4; ++o) outp[g * 4 + o] = l[o] - lse;
  }
}

// ---------------- launch ----------------------------------------------------
extern "C" void kernel_launch(void* const* d_in, const int* in_sizes, int n_in,
                              void* d_out, int out_size, void* d_ws, size_t ws_size,
                              hipStream_t stream) {
  const float* x        = (const float*)d_in[0];
  const int*   ei       = (const int*)d_in[1];
  const int*   batch    = (const int*)d_in[2];
  const float* conv0_w  = (const float*)d_in[3];
  const float* bn0_g    = (const float*)d_in[4];
  const float* bn0_b    = (const float*)d_in[5];
  const float* bn0_m    = (const float*)d_in[6];
  const float* bn0_v    = (const float*)d_in[7];
  const float* conv1_w  = (const float*)d_in[8];
  const float* conv2_w  = (const float*)d_in[9];
  const float* bn2_g    = (const float*)d_in[10];
  const float* bn2_b    = (const float*)d_in[11];
  const float* bn2_m    = (const float*)d_in[12];
  const float* bn2_v    = (const float*)d_in[13];
  const float* g1w1 = (const float*)d_in[14];
  const float* g1b1 = (const float*)d_in[15];
  const float* g1w2 = (const float*)d_in[16];
  const float* g1b2 = (const float*)d_in[17];
  const float* g2w1 = (const float*)d_in[18];
  const float* g2b1 = (const float*)d_in[19];
  const float* g2w2 = (const float*)d_in[20];
  const float* g2b2 = (const float*)d_in[21];
  const float* dw   = (const float*)d_in[22];
  const float* db   = (const float*)d_in[23];

  char* base = (char*)d_ws;
  unsigned short* h0 = (unsigned short*)(base);
  unsigned short* a2 = (unsigned short*)(base);
  unsigned short* a1 = (unsigned short*)(base + 20480000ull);
  unsigned short* z  = (unsigned short*)(base + 40960000ull);
  unsigned short* h1 = (unsigned short*)(base + 71680000ull);
  unsigned short* h2 = h1;
  size_t off = 102400000ull;
  unsigned short* w1T = (unsigned short*)(base + off); off += 786432ull;    // 768x512
  unsigned short* w2T = (unsigned short*)(base + off); off += 1179648ull;   // 768x768
  unsigned short* w3T = (unsigned short*)(base + off); off += 1179648ull;
  unsigned short* w4T = (unsigned short*)(base + off); off += 1179648ull;
  // deg, sums, cnt contiguous -> single memset
  int*   deg     = (int*)(base + off);   off += 80000ull;
  float* sums    = (float*)(base + off); off += 196608ull;   // 64*768 f32
  int*   cnt     = (int*)(base + off);   off += 256ull;
  int*   row_ptr = (int*)(base + off);   off += 80128ull;
  int*   cursor  = (int*)(base + off);   off += 80128ull;
  int*   csr_src = (int*)(base + off);   off += 1280000ull;

  // conv tables live in the a1 region (dead until k_agg<512> writes it)
  float* cwb = (float*)(base + 20480000ull);                       // 3328 f32 used
  unsigned short* tb16 = (unsigned short*)(base + 20480000ull + 16384ull);  // 1536 bf16

  hipMemsetAsync(deg, 0, 80000ull + 196608ull + 256ull, stream);

  k_wprep<<<1, 256, 0, stream>>>(conv0_w, conv1_w, bn0_g, bn0_b, bn0_m, bn0_v,
                                 bn2_g, bn2_b, bn2_m, bn2_v, conv2_w, cwb, tb16);

  // conv blocks [0,5000) + edge-count [5000,6250) + transpose tiles [6250,6778)
  k_conv<<<NN / 4 + 1250 + 528, 256, 0, stream>>>(
      x, h0, ei, deg, g1w1, g1w2, g2w1, g2w2, w1T, w2T, w3T, w4T, cwb, tb16);

  k_scan<<<1, 1024, 0, stream>>>(deg, row_ptr, cursor);
  k_scatter<<<(EE + 255) / 256, 256, 0, stream>>>(ei, cursor, csr_src);

  // GIN1
  k_agg<512><<<NN / 4, 256, 0, stream>>>(h0, row_ptr, csr_src, a1);
  k_gemm<<<480, 256, 0, stream>>>(a1, w1T, g1b1, z, NN, 512, 768);
  k_gemm<<<480, 256, 0, stream>>>(z, w2T, g1b2, h1, NN, 768, 768);
  // GIN2
  k_agg<768><<<NN / 4, 256, 0, stream>>>(h1, row_ptr, csr_src, a2);
  k_gemm<<<480, 256, 0, stream>>>(a2, w3T, g2b1, z, NN, 768, 768);
  k_gemm<<<480, 256, 0, stream>>>(z, w4T, g2b2, h2, NN, 768, 768);

  k_pool1<<<(NN + 31) / 32, 256, 0, stream>>>(h2, batch, sums, cnt);
  k_pool2<<<GG, 64, 0, stream>>>(sums, cnt, dw, db, (float*)d_out);
}

// Round 14
// 478.218 us; speedup vs baseline: 1.1162x; 1.1162x over previous
//
#include <hip/hip_runtime.h>
#include <cstdint>

#define NN 20000
#define TT 256
#define EE 320000
#define GG 64
#define EMBD 768
#define FIND 512

typedef __bf16 bf16x8 __attribute__((ext_vector_type(8)));
typedef float f32x4 __attribute__((ext_vector_type(4)));
typedef unsigned int uint32x4 __attribute__((ext_vector_type(4)));

__device__ __forceinline__ float b2f(unsigned short u) {
  union { unsigned int i; float f; } v; v.i = ((unsigned int)u) << 16; return v.f;
}
__device__ __forceinline__ float b2f_lo(unsigned int u) {
  union { unsigned int i; float f; } v; v.i = u << 16; return v.f;
}
__device__ __forceinline__ float b2f_hi(unsigned int u) {
  union { unsigned int i; float f; } v; v.i = u & 0xFFFF0000u; return v.f;
}
__device__ __forceinline__ unsigned short f2bf(float f) {
  union { float f; unsigned int i; } v; v.f = f;
  unsigned int u = v.i;
  return (unsigned short)((u + 0x7FFFu + ((u >> 16) & 1u)) >> 16);
}
__device__ __forceinline__ unsigned int pack2bf(float lo, float hi) {
  return (unsigned int)f2bf(lo) | ((unsigned int)f2bf(hi) << 16);
}

// async global->LDS, 16B per lane. LDS dest is wave-uniform base + lane*16.
__device__ __forceinline__ void gload_lds16(const void* g, void* l) {
  auto gp = reinterpret_cast<const __attribute__((address_space(1))) char*>(
      reinterpret_cast<uintptr_t>(g));
  auto lp = reinterpret_cast<__attribute__((address_space(3))) char*>(
      (unsigned int)(reinterpret_cast<uintptr_t>(l)));
  __builtin_amdgcn_global_load_lds(gp, lp, 16, 0, 0);
}

// ---------------- weight prep --------------------------------------------
// cwb (f32): [0..423] cw[u*8+c] composed 53-tap; [424..431] zc; [432..439] s0;
// [440..447] o0; [448..463] s2; [464..479] o2;
// [512..1791] KL[t][xi][c] (t<10, xi<16, c<8) boundary-low x-kernel;
// [1792..1871] CL[t][c]; [1920..3199] KH[tt][xi'][c]; [3200..3279] CH[tt][c].
// tb16 (bf16): [0..1023] cwA A-frag table [s][lane][j] (A row=c=l&15,
// k=u=32s+8*(l>>4)+j); [1024..1535] w2 B-frag table [lane][j]
// (B col=k=l&15, kdim=c=8*(l>>4)+j).
__global__ __launch_bounds__(256) void k_wprep(
    const float* __restrict__ w0, const float* __restrict__ w1,
    const float* __restrict__ g0, const float* __restrict__ be0,
    const float* __restrict__ mu0, const float* __restrict__ va0,
    const float* __restrict__ g2, const float* __restrict__ be2,
    const float* __restrict__ mu2, const float* __restrict__ va2,
    const float* __restrict__ w2,
    float* __restrict__ cwb, unsigned short* __restrict__ tb16) {
  const int i = threadIdx.x;
  if (i < 8) {
    float s = g0[i] * rsqrtf(va0[i] + 1e-5f);
    float o = be0[i] - mu0[i] * s;
    float ks = 0.f;
    for (int v = 0; v < 21; ++v) ks += w1[v * 8 + i];
    cwb[424 + i] = o * ks;
    cwb[432 + i] = s;
    cwb[440 + i] = o;
  }
  if (i < 16) {
    float s2 = g2[i] * rsqrtf(va2[i] + 1e-5f);
    cwb[448 + i] = s2;
    cwb[464 + i] = be2[i] - mu2[i] * s2;
  }
  for (int e = i; e < 424; e += 256) {
    int u = e >> 3, c = e & 7;
    float s = g0[c] * rsqrtf(va0[c] + 1e-5f);
    float acc = 0.f;
    int v0 = u - 32; if (v0 < 0) v0 = 0;
    int v1 = u; if (v1 > 20) v1 = 20;
    for (int v = v0; v <= v1; ++v) acc += w1[v * 8 + c] * w0[(u - v) * 8 + c];
    cwb[e] = s * acc;
  }
  __syncthreads();
  // KL: corr_lo[t][c] = CL + sum_xi x[xi]*KL[t][xi][c]
  for (int e = i; e < 1280; e += 256) {
    int t = e >> 7, xi = (e >> 3) & 15, c = e & 7;
    float s = cwb[432 + c];
    float a = 0.f;
    for (int p = t - 10; p <= -1; ++p) {
      int wi = xi - p + 16, v = p - t + 10;
      if (wi >= 0 && wi < 33) a += w0[wi * 8 + c] * w1[v * 8 + c];
    }
    cwb[512 + e] = s * a;
  }
  for (int e = i; e < 80; e += 256) {
    int t = e >> 3, c = e & 7;
    float a = 0.f;
    for (int v = 0; v <= 9 - t; ++v) a += w1[v * 8 + c];
    cwb[1792 + e] = cwb[440 + c] * a;
  }
  // KH: hi side, t = 246+tt, xi = 240+xi'
  for (int e = i; e < 1280; e += 256) {
    int tt = e >> 7, xi = 240 + ((e >> 3) & 15), c = e & 7;
    int t = 246 + tt;
    float s = cwb[432 + c];
    float a = 0.f;
    for (int p = 256; p <= t + 10; ++p) {
      int wi = xi - p + 16, v = p - t + 10;
      if (wi >= 0 && wi < 33) a += w0[wi * 8 + c] * w1[v * 8 + c];
    }
    cwb[1920 + e] = s * a;
  }
  for (int e = i; e < 80; e += 256) {
    int tt = e >> 3, c = e & 7;
    float a = 0.f;
    for (int v = 20 - tt; v <= 20; ++v) a += w1[v * 8 + c];
    cwb[3200 + e] = cwb[440 + c] * a;
  }
  // cwA A-frag table: [s][l][j] -> cw[u][c], zero-padded (u>=53 or c>=8)
  for (int e = i; e < 1024; e += 256) {
    int s = e >> 9, l = (e >> 3) & 63, j = e & 7;
    int c = l & 15, u = 32 * s + 8 * (l >> 4) + j;
    float v = (c < 8 && u < 53) ? cwb[u * 8 + c] : 0.f;
    tb16[e] = f2bf(v);
  }
  // w2 B-frag table: [l][j] -> w2[c][k], zero for c>=8
  for (int e = i; e < 512; e += 256) {
    int l = e >> 3, j = e & 7;
    int c = 8 * (l >> 4) + j, k = l & 15;
    float v = (c < 8) ? w2[c * 16 + k] : 0.f;
    tb16[1024 + e] = f2bf(v);
  }
}

// ---------------- fused conv (MFMA) + init ---------------------------------
// r6 conv (structure asymptote). 1 wave per node; composed 53-tap conv as
// MFMA; bf16 parity copies; boundary corrections via precomputed tables.
// r12 init path: weight transposes TILED through LDS (64x64 tiles, 528
// tile-blocks) — verified: conv FETCH 41.5->15 MB.
__global__ __launch_bounds__(256, 3) void k_conv(
    const float* __restrict__ x,
    unsigned short* __restrict__ out,
    const int* __restrict__ ei, int* __restrict__ deg,
    const float* __restrict__ g1w1, const float* __restrict__ g1w2,
    const float* __restrict__ g2w1, const float* __restrict__ g2w2,
    unsigned short* __restrict__ w1T, unsigned short* __restrict__ w2T,
    unsigned short* __restrict__ w3T, unsigned short* __restrict__ w4T,
    const float* __restrict__ cwb, const unsigned short* __restrict__ tb16) {
  __shared__ __align__(16) float xls[4][344];              // idx = x_t + 28
  __shared__ __align__(16) unsigned short xbf[4][4][360];  // parity copies
  __shared__ __align__(16) float tls[64][65];              // transpose tile
  const int tid = threadIdx.x;

  if (blockIdx.x >= NN / 4) {
    // ---- init path (block-uniform branch) ----
    int b = blockIdx.x - NN / 4;
    if (b < 1250) {                   // edge-count: 1250*256 >= EE
      int e = b * 256 + tid;
      if (e < EE) atomicAdd(&deg[ei[EE + e]], 1);
    } else {                          // tiled weight transposes (528 blocks)
      int b2 = b - 1250;
      const float* src; unsigned short* dst; int KD; int tt;
      if (b2 < 96) { src = g1w1; dst = w1T; KD = 512; tt = b2; }
      else {
        int j = b2 - 96;
        int which = j / 144;          // 0..2
        tt = j - which * 144;
        KD = 768;
        src = which == 0 ? g1w2 : (which == 1 ? g2w1 : g2w2);
        dst = which == 0 ? w2T : (which == 1 ? w3T : w4T);
      }
      int nt = tt % 12, kt = tt / 12;
      int n0 = nt * 64, k0 = kt * 64; // dst rows n0.., dst cols k0..
      int r = tid >> 2, cq = tid & 3;
      // read src 64x64 tile (rows k0+r of 768-col src), coalesced float4
      const float* sp = src + (size_t)(k0 + r) * 768 + n0 + cq * 16;
      #pragma unroll
      for (int j = 0; j < 4; ++j) {
        float4 v = *(const float4*)(sp + 4 * j);
        tls[r][cq * 16 + 4 * j + 0] = v.x;
        tls[r][cq * 16 + 4 * j + 1] = v.y;
        tls[r][cq * 16 + 4 * j + 2] = v.z;
        tls[r][cq * 16 + 4 * j + 3] = v.w;
      }
      __syncthreads();
      // write dst row n0+r, cols k0+cq*16 .. +15 (32B packed bf16)
      unsigned int p0 = pack2bf(tls[cq * 16 + 0][r],  tls[cq * 16 + 1][r]);
      unsigned int p1 = pack2bf(tls[cq * 16 + 2][r],  tls[cq * 16 + 3][r]);
      unsigned int p2 = pack2bf(tls[cq * 16 + 4][r],  tls[cq * 16 + 5][r]);
      unsigned int p3 = pack2bf(tls[cq * 16 + 6][r],  tls[cq * 16 + 7][r]);
      unsigned int p4 = pack2bf(tls[cq * 16 + 8][r],  tls[cq * 16 + 9][r]);
      unsigned int p5 = pack2bf(tls[cq * 16 + 10][r], tls[cq * 16 + 11][r]);
      unsigned int p6 = pack2bf(tls[cq * 16 + 12][r], tls[cq * 16 + 13][r]);
      unsigned int p7 = pack2bf(tls[cq * 16 + 14][r], tls[cq * 16 + 15][r]);
      unsigned short* dp = dst + (size_t)(n0 + r) * KD + k0 + cq * 16;
      uint4 o0; o0.x = p0; o0.y = p1; o0.z = p2; o0.w = p3;
      uint4 o1; o1.x = p4; o1.y = p5; o1.z = p6; o1.w = p7;
      *(uint4*)(dp) = o0;
      *(uint4*)(dp + 8) = o1;
    }
    return;
  }

  // ---- conv path ----
  const int wv = tid >> 6;            // node slot within block
  const int l = tid & 63;
  const int n = blockIdx.x * 4 + wv;
  const int hi = l >> 4, tl = l & 15;

  // stage x (f32) + zero halos: idx [0,28) and [284,344)
  float4 xv4 = *(const float4*)(x + (size_t)n * TT + 4 * l);
  *(float4*)&xls[wv][28 + 4 * l] = xv4;
  float4 z4 = make_float4(0.f, 0.f, 0.f, 0.f);
  if (l < 7) *(float4*)&xls[wv][4 * l] = z4;
  else if (l < 22) *(float4*)&xls[wv][284 + 4 * (l - 7)] = z4;
  __syncthreads();

  // ---- staging phase (between barriers): bf16 parity copies + corr ----
  {
    float4 f0 = *(const float4*)&xls[wv][4 * l];
    float4 f1 = *(const float4*)&xls[wv][4 * l + 4];
    unsigned int b0 = f2bf(f0.x), b1 = f2bf(f0.y), b2 = f2bf(f0.z), b3 = f2bf(f0.w);
    unsigned int b4 = f2bf(f1.x), b5 = f2bf(f1.y), b6 = f2bf(f1.z);
    uint2 w;
    w.x = b0 | (b1 << 16); w.y = b2 | (b3 << 16);
    *(uint2*)&xbf[wv][0][4 * l] = w;
    w.x = b1 | (b2 << 16); w.y = b3 | (b4 << 16);
    *(uint2*)&xbf[wv][1][4 * l] = w;
    w.x = b2 | (b3 << 16); w.y = b4 | (b5 << 16);
    *(uint2*)&xbf[wv][2][4 * l] = w;
    w.x = b3 | (b4 << 16); w.y = b5 | (b6 << 16);
    *(uint2*)&xbf[wv][3][4 * l] = w;
  }
  if (l < 21) {
    float4 f0 = *(const float4*)&xls[wv][256 + 4 * l];
    float4 f1 = *(const float4*)&xls[wv][256 + 4 * l + 4];
    unsigned int b0 = f2bf(f0.x), b1 = f2bf(f0.y), b2 = f2bf(f0.z), b3 = f2bf(f0.w);
    unsigned int b4 = f2bf(f1.x), b5 = f2bf(f1.y), b6 = f2bf(f1.z);
    uint2 w;
    w.x = b0 | (b1 << 16); w.y = b2 | (b3 << 16);
    *(uint2*)&xbf[wv][0][256 + 4 * l] = w;
    w.x = b1 | (b2 << 16); w.y = b3 | (b4 << 16);
    *(uint2*)&xbf[wv][1][256 + 4 * l] = w;
    w.x = b2 | (b3 << 16); w.y = b4 | (b5 << 16);
    *(uint2*)&xbf[wv][2][256 + 4 * l] = w;
    w.x = b3 | (b4 << 16); w.y = b5 | (b6 << 16);
    *(uint2*)&xbf[wv][3][256 + 4 * l] = w;
  }

  // boundary corrections (exact, linear in x[0..15] / x[240..255]);
  // zero for non-boundary lanes, applied at m=0 / m=15 in the loop.
  const float* xp = xls[wv];
  float corrL[4] = {0.f, 0.f, 0.f, 0.f};
  float corrH[4] = {0.f, 0.f, 0.f, 0.f};
  if (hi < 2 && tl < 10) {
    float4 c4 = *(const float4*)&cwb[1792 + tl * 8 + hi * 4];
    corrL[0] = c4.x; corrL[1] = c4.y; corrL[2] = c4.z; corrL[3] = c4.w;
    #pragma unroll
    for (int xi = 0; xi < 16; ++xi) {
      float xv = xp[28 + xi];
      float4 k4 = *(const float4*)&cwb[512 + (tl * 16 + xi) * 8 + hi * 4];
      corrL[0] += xv * k4.x; corrL[1] += xv * k4.y;
      corrL[2] += xv * k4.z; corrL[3] += xv * k4.w;
    }
  }
  if (hi < 2 && tl >= 6) {
    int tt = tl - 6;
    float4 c4 = *(const float4*)&cwb[3200 + tt * 8 + hi * 4];
    corrH[0] = c4.x; corrH[1] = c4.y; corrH[2] = c4.z; corrH[3] = c4.w;
    #pragma unroll
    for (int xi = 0; xi < 16; ++xi) {
      float xv = xp[268 + xi];
      float4 k4 = *(const float4*)&cwb[1920 + (tt * 16 + xi) * 8 + hi * 4];
      corrH[0] += xv * k4.x; corrH[1] += xv * k4.y;
      corrH[2] += xv * k4.z; corrH[3] += xv * k4.w;
    }
  }
  __syncthreads();

  // fragment tables (L1-hot, shared by all waves)
  const bf16x8* frp = (const bf16x8*)tb16;
  bf16x8 cwA0 = frp[l];
  bf16x8 cwA1 = frp[64 + l];
  bf16x8 w2f  = frp[128 + l];
  float4 zc4 = *(const float4*)&cwb[424 + (hi & 1) * 4];  // zc[c], c=(hi&1)*4+r
  float s2k = cwb[448 + tl], o2k = cwb[464 + tl];
  const f32x4 zero4 = {0.f, 0.f, 0.f, 0.f};

  // per-lane parity copy + element base: E0(k) = 16k + tl + 8hi + 2
  const int sl = (tl + 2) & 3;
  const char* cb = (const char*)&xbf[wv][sl][0];
  const int ebase = ((tl + 2) & ~3) + 8 * hi;   // (E0(0) - sl), multiple of 4

  // G(k) = frag at E0(k): 8 bf16 at copy index ebase + 16k — preloaded
#define LDF(kk) ({                                                        \
    uint2 _lo = *(const uint2*)(cb + 2 * (ebase + 16 * (kk)));            \
    uint2 _hi = *(const uint2*)(cb + 2 * (ebase + 16 * (kk)) + 8);        \
    __builtin_bit_cast(bf16x8, (uint32x4){_lo.x, _lo.y, _hi.x, _hi.y});   \
  })
  bf16x8 G[18];
  #pragma unroll
  for (int k = 0; k < 18; ++k) G[k] = LDF(k);
#undef LDF

  unsigned short* outn = out + (size_t)n * FIND;

  #pragma unroll
  for (int m = 0; m < 16; ++m) {
    f32x4 acc = zero4;
    acc = __builtin_amdgcn_mfma_f32_16x16x32_bf16(cwA0, G[m], acc, 0, 0, 0);
    acc = __builtin_amdgcn_mfma_f32_16x16x32_bf16(cwA1, G[m + 2], acc, 0, 0, 0);
    float zf[4];
    #pragma unroll
    for (int r = 0; r < 4; ++r) zf[r] = acc[r] + zc4[r];
    if (m == 0) {
      #pragma unroll
      for (int r = 0; r < 4; ++r) zf[r] -= corrL[r];
    } else if (m == 15) {
      #pragma unroll
      for (int r = 0; r < 4; ++r) zf[r] -= corrH[r];
    }

    // relu + pack to bf16 pairs, 2 shfls for partner half (c 4..7)
    unsigned int q0 = pack2bf(fmaxf(zf[0], 0.f), fmaxf(zf[1], 0.f));
    unsigned int q1 = pack2bf(fmaxf(zf[2], 0.f), fmaxf(zf[3], 0.f));
    unsigned int p0 = __shfl_xor(q0, 16);
    unsigned int p1 = __shfl_xor(q1, 16);
    bf16x8 a2 = __builtin_bit_cast(bf16x8, (uint32x4){q0, q1, p0, p1});
    f32x4 pacc = __builtin_amdgcn_mfma_f32_16x16x32_bf16(a2, w2f, zero4, 0, 0, 0);

    // bn2 + relu + mean-pool over 8 t; D2: row t=(l>>4)*4+r, col k=tl
    float v = 0.f;
    #pragma unroll
    for (int r = 0; r < 4; ++r) v += fmaxf(pacc[r] * s2k + o2k, 0.f);
    v += __shfl_xor(v, 16);
    v *= 0.125f;
    if (hi == 0)      outn[(2 * m) * 16 + tl]     = f2bf(v);
    else if (hi == 2) outn[(2 * m + 1) * 16 + tl] = f2bf(v);
  }
}

// ---------------- scan: register-serial, 20 elems/thread, one block ---------
__global__ __launch_bounds__(1024) void k_scan(const int* __restrict__ deg,
                                               int* __restrict__ row_ptr,
                                               int* __restrict__ cursor) {
  __shared__ int wsums[16];
  const int tid = threadIdx.x, lane = tid & 63, wid = tid >> 6;
  const int base = tid * 20;
  int v[20];
  int s = 0;
  #pragma unroll
  for (int i = 0; i < 20; ++i) {
    int idx = base + i;
    int d = (idx < NN) ? deg[idx] : 0;
    v[i] = s;                // local exclusive prefix
    s += d;
  }
  int inc = s;
  #pragma unroll
  for (int off = 1; off < 64; off <<= 1) {
    int t = __shfl_up(inc, off);
    if (lane >= off) inc += t;
  }
  if (lane == 63) wsums[wid] = inc;
  __syncthreads();
  if (wid == 0) {
    int ws = (lane < 16) ? wsums[lane] : 0;
    #pragma unroll
    for (int off = 1; off < 16; off <<= 1) {
      int t = __shfl_up(ws, off);
      if (lane >= off) ws += t;
    }
    if (lane < 16) wsums[lane] = ws;   // inclusive wave-sum prefix
    if (lane == 15) row_ptr[NN] = ws;  // grand total
  }
  __syncthreads();
  int woff = (wid > 0) ? wsums[wid - 1] : 0;
  int texcl = woff + inc - s;
  #pragma unroll
  for (int i = 0; i < 20; ++i) {
    int idx = base + i;
    if (idx < NN) { int e = texcl + v[i]; row_ptr[idx] = e; cursor[idx] = e; }
  }
}

__global__ void k_scatter(const int* __restrict__ ei, int* __restrict__ cursor,
                          int* __restrict__ csr_src) {
  int e = blockIdx.x * 256 + threadIdx.x;
  if (e < EE) {
    int d = ei[EE + e];
    int pos = atomicAdd(&cursor[d], 1);
    csr_src[pos] = ei[e];
  }
}

// ---------------- aggregation: out[n] = h[n] + sum_{e in(n)} h[src[e]] ------
// r11 form: edge loop unrolled x8; LLC-BW-bound (x8 vs x4 was neutral).
template <int KK>
__global__ __launch_bounds__(256) void k_agg(const unsigned short* __restrict__ h,
                                             const int* __restrict__ rp,
                                             const int* __restrict__ csr,
                                             unsigned short* __restrict__ out) {
  const int node = blockIdx.x * 4 + (threadIdx.x >> 6);
  const int lane = threadIdx.x & 63;
  constexpr int NE = (KK == 512) ? 8 : 12;
  float acc[NE];
  {
    const char* hp = (const char*)(h + (size_t)node * KK);
    uint4 v = *(const uint4*)(hp + lane * 16);
    acc[0] = b2f_lo(v.x); acc[1] = b2f_hi(v.x);
    acc[2] = b2f_lo(v.y); acc[3] = b2f_hi(v.y);
    acc[4] = b2f_lo(v.z); acc[5] = b2f_hi(v.z);
    acc[6] = b2f_lo(v.w); acc[7] = b2f_hi(v.w);
    if (KK == 768) {
      uint2 w = *(const uint2*)(hp + 1024 + lane * 8);
      acc[8] = b2f_lo(w.x); acc[9] = b2f_hi(w.x);
      acc[10] = b2f_lo(w.y); acc[11] = b2f_hi(w.y);
    }
  }
  int s = rp[node], e = rp[node + 1];
  int i = s;
  for (; i + 8 <= e; i += 8) {
    const char* sp[8];
    #pragma unroll
    for (int u = 0; u < 8; ++u)
      sp[u] = (const char*)(h + (size_t)csr[i + u] * KK);
    uint4 v[8];
    #pragma unroll
    for (int u = 0; u < 8; ++u) v[u] = *(const uint4*)(sp[u] + lane * 16);
    uint2 w[8];
    if (KK == 768) {
      #pragma unroll
      for (int u = 0; u < 8; ++u)
        w[u] = *(const uint2*)(sp[u] + 1024 + lane * 8);
    }
    #pragma unroll
    for (int u = 0; u < 8; ++u) {
      acc[0] += b2f_lo(v[u].x); acc[1] += b2f_hi(v[u].x);
      acc[2] += b2f_lo(v[u].y); acc[3] += b2f_hi(v[u].y);
      acc[4] += b2f_lo(v[u].z); acc[5] += b2f_hi(v[u].z);
      acc[6] += b2f_lo(v[u].w); acc[7] += b2f_hi(v[u].w);
      if (KK == 768) {
        acc[8]  += b2f_lo(w[u].x); acc[9]  += b2f_hi(w[u].x);
        acc[10] += b2f_lo(w[u].y); acc[11] += b2f_hi(w[u].y);
      }
    }
  }
  for (; i + 4 <= e; i += 4) {
    const char* sp[4];
    #pragma unroll
    for (int u = 0; u < 4; ++u)
      sp[u] = (const char*)(h + (size_t)csr[i + u] * KK);
    uint4 v[4];
    #pragma unroll
    for (int u = 0; u < 4; ++u) v[u] = *(const uint4*)(sp[u] + lane * 16);
    uint2 w[4];
    if (KK == 768) {
      #pragma unroll
      for (int u = 0; u < 4; ++u)
        w[u] = *(const uint2*)(sp[u] + 1024 + lane * 8);
    }
    #pragma unroll
    for (int u = 0; u < 4; ++u) {
      acc[0] += b2f_lo(v[u].x); acc[1] += b2f_hi(v[u].x);
      acc[2] += b2f_lo(v[u].y); acc[3] += b2f_hi(v[u].y);
      acc[4] += b2f_lo(v[u].z); acc[5] += b2f_hi(v[u].z);
      acc[6] += b2f_lo(v[u].w); acc[7] += b2f_hi(v[u].w);
      if (KK == 768) {
        acc[8]  += b2f_lo(w[u].x); acc[9]  += b2f_hi(w[u].x);
        acc[10] += b2f_lo(w[u].y); acc[11] += b2f_hi(w[u].y);
      }
    }
  }
  for (; i < e; ++i) {
    const char* sp = (const char*)(h + (size_t)csr[i] * KK);
    uint4 v = *(const uint4*)(sp + lane * 16);
    acc[0] += b2f_lo(v.x); acc[1] += b2f_hi(v.x);
    acc[2] += b2f_lo(v.y); acc[3] += b2f_hi(v.y);
    acc[4] += b2f_lo(v.z); acc[5] += b2f_hi(v.z);
    acc[6] += b2f_lo(v.w); acc[7] += b2f_hi(v.w);
    if (KK == 768) {
      uint2 w = *(const uint2*)(sp + 1024 + lane * 8);
      acc[8] += b2f_lo(w.x); acc[9] += b2f_hi(w.x);
      acc[10] += b2f_lo(w.y); acc[11] += b2f_hi(w.y);
    }
  }
  char* op = (char*)(out + (size_t)node * KK);
  uint4 v;
  v.x = pack2bf(acc[0], acc[1]); v.y = pack2bf(acc[2], acc[3]);
  v.z = pack2bf(acc[4], acc[5]); v.w = pack2bf(acc[6], acc[7]);
  *(uint4*)(op + lane * 16) = v;
  if (KK == 768) {
    uint2 w;
    w.x = pack2bf(acc[8], acc[9]); w.y = pack2bf(acc[10], acc[11]);
    *(uint2*)(op + 1024 + lane * 8) = w;
  }
}

// ---------------- GEMM: C(M,Nn) = relu(A(M,K) @ Bt(Nn,K)^T + bias) ----------
// r14: 256x256 tile, 512 threads (8 waves, 2Mx4N), BK=32, THREE-buffer
// 2-deep counted-vmcnt pipeline (r9 discipline, proven correct). Why:
// r13's GEMM runs at 315 TF = exactly the m102 shape-curve ceiling of the
// 2-generation 128x256 structure. 237 blocks (79 M-tiles x 3 N-tiles) is a
// SINGLE generation on 256 CUs (no serialized second wave of blocks), and
// the bigger tile stages 33% fewer LDS bytes per FLOP. Stage = 4
// gload_lds/thread -> counted vmcnt(4) keeps S(t+2) in flight across each
// raw s_barrier (never drains to 0 in the loop). Chunk/fragment scheme is
// the proven conflict-free one; MFMA K=32 per call keeps accumulation order
// bit-identical. Bijective chunked XCD swizzle (m204): the 3 N-blocks
// sharing an A M-tile get consecutive wgids on ONE XCD -> A panel L2-hits.
// LDS 96KB (1 block/CU). Epilogue through LDS (full-sector stores, r13).
#define GEMM_GRID 237
__global__ __launch_bounds__(512, 1) void k_gemm(const unsigned short* __restrict__ A,
                                                 const unsigned short* __restrict__ Bt,
                                                 const float* __restrict__ bias,
                                                 unsigned short* __restrict__ C,
                                                 int M, int K, int Nn) {
  __shared__ __align__(16) unsigned short As[3][256 * 32];  // 16 KB per buf
  __shared__ __align__(16) unsigned short Bs[3][256 * 32];  // 16 KB per buf

  // bijective chunked xcd swizzle: nwg=237, q=29, r=5
  const int id = blockIdx.x;
  const int xcd = id & 7, jj = id >> 3;
  const int wg = (xcd < 5 ? xcd * 30 : 5 * 30 + (xcd - 5) * 29) + jj;
  const int m_tile = wg / 3, ntile = wg % 3;
  const int m0 = m_tile * 256;
  const int n0 = ntile * 256;

  const int tid = threadIdx.x;
  const int wave = tid >> 6, lane = tid & 63;
  const int wr = wave >> 2, wc = wave & 3;   // 2 x 4 wave grid; 128x64 each

  f32x4 zero = {0.f, 0.f, 0.f, 0.f};
  f32x4 acc[8][4];
  #pragma unroll
  for (int mt = 0; mt < 8; ++mt)
    #pragma unroll
    for (int nt = 0; nt < 4; ++nt) acc[mt][nt] = zero;

  // chunk scheme per buffer: 16 row-tiles of 16 rows x 32 k; per tile 64
  // chunks of 16B: c in [0,64): row=c&15, koff=(c>>4)*8. 1024 chunks = 16KB.
  // Fragment: lane l reads chunk (tile*64 + l): row=l&15, k=8*(l>>4)+j ->
  // the proven 16x16x32 operand layout, conflict-free.
#define STAGE(buf, kk0)                                                      \
  {                                                                          \
    _Pragma("unroll")                                                        \
    for (int j2 = 0; j2 < 2; ++j2) {                                         \
      int chunk = j2 * 512 + tid;                                            \
      int tile = chunk >> 6, c = chunk & 63;                                 \
      int row = tile * 16 + (c & 15);                                        \
      int koff = (c >> 4) * 8;                                               \
      int gm = m0 + row; if (gm >= M) gm = 0;                                \
      gload_lds16(A + (size_t)gm * K + (kk0) + koff,                         \
                  (char*)&As[buf][0] + chunk * 16);                          \
    }                                                                        \
    _Pragma("unroll")                                                        \
    for (int j2 = 0; j2 < 2; ++j2) {                                         \
      int chunk = j2 * 512 + tid;                                            \
      int tile = chunk >> 6, c = chunk & 63;                                 \
      int row = tile * 16 + (c & 15);                                        \
      int koff = (c >> 4) * 8;                                               \
      gload_lds16(Bt + (size_t)(n0 + row) * K + (kk0) + koff,                \
                  (char*)&Bs[buf][0] + chunk * 16);                          \
    }                                                                        \
  }

  const int nsteps = K >> 5;          // 16 (K=512) or 24 (K=768)
  STAGE(0, 0);
  STAGE(1, 32);
  asm volatile("s_waitcnt vmcnt(4)" ::: "memory");   // S(0) landed
  __builtin_amdgcn_sched_barrier(0);
  __builtin_amdgcn_s_barrier();

  int cur = 0, nx2 = 2;
  for (int t = 0; t < nsteps; ++t) {
    if (t + 2 < nsteps) STAGE(nx2, (t + 2) * 32);    // 2-deep prefetch
    bf16x8 bfr[4];
    #pragma unroll
    for (int nt = 0; nt < 4; ++nt)
      bfr[nt] = *(const bf16x8*)((const char*)&Bs[cur][0] +
                                 (((wc * 4 + nt) * 64 + lane) * 16));
    __builtin_amdgcn_s_setprio(1);
    #pragma unroll
    for (int mt = 0; mt < 8; ++mt) {
      bf16x8 af = *(const bf16x8*)((const char*)&As[cur][0] +
                                   (((wr * 8 + mt) * 64 + lane) * 16));
      #pragma unroll
      for (int nt = 0; nt < 4; ++nt)
        acc[mt][nt] = __builtin_amdgcn_mfma_f32_16x16x32_bf16(af, bfr[nt], acc[mt][nt], 0, 0, 0);
    }
    __builtin_amdgcn_s_setprio(0);
    if (t + 1 < nsteps) {
      if (t + 2 < nsteps)
        asm volatile("s_waitcnt vmcnt(4)" ::: "memory");  // S(t+1) landed; S(t+2) in flight
      else
        asm volatile("s_waitcnt vmcnt(0)" ::: "memory");  // tail drain
      __builtin_amdgcn_sched_barrier(0);
      __builtin_amdgcn_s_barrier();
    }
    cur = (cur == 2) ? 0 : cur + 1;
    nx2 = (nx2 == 2) ? 0 : nx2 + 1;
  }
#undef STAGE

  // ---- epilogue through LDS: 8 tiles of 32 rows x 256 cols (reuses As) ----
  const int q4 = lane >> 4, ccol = lane & 15;
  unsigned short* els = &As[0][0];    // 32*256 u16 = 16 KB
  float bv[4];
  #pragma unroll
  for (int nt = 0; nt < 4; ++nt) bv[nt] = bias[n0 + wc * 64 + nt * 16 + ccol];
  #pragma unroll
  for (int e = 0; e < 8; ++e) {
    __syncthreads();  // prior reads of els done (K-loop for e=0)
    if ((e >> 2) == wr) {
      #pragma unroll
      for (int mtl = 0; mtl < 2; ++mtl) {
        int mt = (e & 3) * 2 + mtl;
        #pragma unroll
        for (int nt = 0; nt < 4; ++nt) {
          #pragma unroll
          for (int r2 = 0; r2 < 4; ++r2) {
            float v = acc[mt][nt][r2] + bv[nt];
            v = v > 0.f ? v : 0.f;
            els[(mtl * 16 + q4 * 4 + r2) * 256 + wc * 64 + nt * 16 + ccol] = f2bf(v);
          }
        }
      }
    }
    __syncthreads();
    // 32 rows x 512B; 16 threads/row, 32B each — full-sector coalesced
    int rl = tid >> 4, seg = tid & 15;
    int grow = m0 + e * 32 + rl;
    if (grow < M) {
      const uint4* lp = (const uint4*)&els[rl * 256 + seg * 16];
      uint4 v0 = lp[0], v1 = lp[1];
      uint4* gp = (uint4*)&C[(size_t)grow * Nn + n0 + seg * 16];
      gp[0] = v0; gp[1] = v1;
    }
  }
}

// ---------------- pool phase 1: per-graph sums (grid-wide, sorted batch) ----
// 32 nodes/block (625 blocks).
__global__ __launch_bounds__(256) void k_pool1(const unsigned short* __restrict__ h,
                                               const int* __restrict__ batch,
                                               float* __restrict__ sums,
                                               int* __restrict__ cnt) {
  const int tid = threadIdx.x;
  const int n0 = blockIdx.x * 32;
  const int n1 = min(n0 + 32, NN);
  int curg = batch[n0];
  float a0 = 0.f, a1 = 0.f, a2 = 0.f;
  int c = 0;
  for (int n = n0; n < n1; ++n) {
    int g = batch[n];  // uniform across block
    if (g != curg) {
      atomicAdd(&sums[curg * EMBD + tid], a0);
      atomicAdd(&sums[curg * EMBD + tid + 256], a1);
      atomicAdd(&sums[curg * EMBD + tid + 512], a2);
      if (tid == 0) atomicAdd(&cnt[curg], c);
      a0 = a1 = a2 = 0.f; c = 0; curg = g;
    }
    const unsigned short* hp = h + (size_t)n * EMBD;
    a0 += b2f(hp[tid]); a1 += b2f(hp[tid + 256]); a2 += b2f(hp[tid + 512]);
    ++c;
  }
  atomicAdd(&sums[curg * EMBD + tid], a0);
  atomicAdd(&sums[curg * EMBD + tid + 256], a1);
  atomicAdd(&sums[curg * EMBD + tid + 512], a2);
  if (tid == 0) atomicAdd(&cnt[curg], c);
}

// ---------------- pool phase 2: dense 768->4 + log_softmax ------------------
__global__ __launch_bounds__(64) void k_pool2(const float* __restrict__ sums,
                                              const int* __restrict__ cnt,
                                              const float* __restrict__ dw,
                                              const float* __restrict__ db,
                                              float* __restrict__ outp) {
  int g = blockIdx.x, lane = threadIdx.x;
  float inv = 1.f / fmaxf((float)cnt[g], 1.f);
  float po[4] = {0.f, 0.f, 0.f, 0.f};
  #pragma unroll
  for (int i = 0; i < 12; ++i) {
    int f = lane + i * 64;
    float pv = sums[g * EMBD + f] * inv;
    #pragma unroll
    for (int o = 0; o < 4; ++o) po[o] += pv * dw[f * 4 + o];
  }
  #pragma unroll
  for (int o = 0; o < 4; ++o) {
    #pragma unroll
    for (int s = 1; s < 64; s <<= 1) po[o] += __shfl_xor(po[o], s);
  }
  if (lane == 0) {
    float l[4], m = -1e30f;
    #pragma unroll
    for (int o = 0; o < 4; ++o) { l[o] = po[o] + db[o]; m = fmaxf(m, l[o]); }
    float sum = 0.f;
    #pragma unroll
    for (int o = 0; o < 4; ++o) sum += expf(l[o] - m);
    float lse = m + logf(sum);
    #pragma unroll
    for (int o = 0; o < 4; ++o) outp[g * 4 + o] = l[o] - lse;
  }
}

// ---------------- launch ----------------------------------------------------
extern "C" void kernel_launch(void* const* d_in, const int* in_sizes, int n_in,
                              void* d_out, int out_size, void* d_ws, size_t ws_size,
                              hipStream_t stream) {
  const float* x        = (const float*)d_in[0];
  const int*   ei       = (const int*)d_in[1];
  const int*   batch    = (const int*)d_in[2];
  const float* conv0_w  = (const float*)d_in[3];
  const float* bn0_g    = (const float*)d_in[4];
  const float* bn0_b    = (const float*)d_in[5];
  const float* bn0_m    = (const float*)d_in[6];
  const float* bn0_v    = (const float*)d_in[7];
  const float* conv1_w  = (const float*)d_in[8];
  const float* conv2_w  = (const float*)d_in[9];
  const float* bn2_g    = (const float*)d_in[10];
  const float* bn2_b    = (const float*)d_in[11];
  const float* bn2_m    = (const float*)d_in[12];
  const float* bn2_v    = (const float*)d_in[13];
  const float* g1w1 = (const float*)d_in[14];
  const float* g1b1 = (const float*)d_in[15];
  const float* g1w2 = (const float*)d_in[16];
  const float* g1b2 = (const float*)d_in[17];
  const float* g2w1 = (const float*)d_in[18];
  const float* g2b1 = (const float*)d_in[19];
  const float* g2w2 = (const float*)d_in[20];
  const float* g2b2 = (const float*)d_in[21];
  const float* dw   = (const float*)d_in[22];
  const float* db   = (const float*)d_in[23];

  char* base = (char*)d_ws;
  unsigned short* h0 = (unsigned short*)(base);
  unsigned short* a2 = (unsigned short*)(base);
  unsigned short* a1 = (unsigned short*)(base + 20480000ull);
  unsigned short* z  = (unsigned short*)(base + 40960000ull);
  unsigned short* h1 = (unsigned short*)(base + 71680000ull);
  unsigned short* h2 = h1;
  size_t off = 102400000ull;
  unsigned short* w1T = (unsigned short*)(base + off); off += 786432ull;    // 768x512
  unsigned short* w2T = (unsigned short*)(base + off); off += 1179648ull;   // 768x768
  unsigned short* w3T = (unsigned short*)(base + off); off += 1179648ull;
  unsigned short* w4T = (unsigned short*)(base + off); off += 1179648ull;
  // deg, sums, cnt contiguous -> single memset
  int*   deg     = (int*)(base + off);   off += 80000ull;
  float* sums    = (float*)(base + off); off += 196608ull;   // 64*768 f32
  int*   cnt     = (int*)(base + off);   off += 256ull;
  int*   row_ptr = (int*)(base + off);   off += 80128ull;
  int*   cursor  = (int*)(base + off);   off += 80128ull;
  int*   csr_src = (int*)(base + off);   off += 1280000ull;

  // conv tables live in the a1 region (dead until k_agg<512> writes it)
  float* cwb = (float*)(base + 20480000ull);                       // 3328 f32 used
  unsigned short* tb16 = (unsigned short*)(base + 20480000ull + 16384ull);  // 1536 bf16

  hipMemsetAsync(deg, 0, 80000ull + 196608ull + 256ull, stream);

  k_wprep<<<1, 256, 0, stream>>>(conv0_w, conv1_w, bn0_g, bn0_b, bn0_m, bn0_v,
                                 bn2_g, bn2_b, bn2_m, bn2_v, conv2_w, cwb, tb16);

  // conv blocks [0,5000) + edge-count [5000,6250) + transpose tiles [6250,6778)
  k_conv<<<NN / 4 + 1250 + 528, 256, 0, stream>>>(
      x, h0, ei, deg, g1w1, g1w2, g2w1, g2w2, w1T, w2T, w3T, w4T, cwb, tb16);

  k_scan<<<1, 1024, 0, stream>>>(deg, row_ptr, cursor);
  k_scatter<<<(EE + 255) / 256, 256, 0, stream>>>(ei, cursor, csr_src);

  // GIN1
  k_agg<512><<<NN / 4, 256, 0, stream>>>(h0, row_ptr, csr_src, a1);
  k_gemm<<<GEMM_GRID, 512, 0, stream>>>(a1, w1T, g1b1, z, NN, 512, 768);
  k_gemm<<<GEMM_GRID, 512, 0, stream>>>(z, w2T, g1b2, h1, NN, 768, 768);
  // GIN2
  k_agg<768><<<NN / 4, 256, 0, stream>>>(h1, row_ptr, csr_src, a2);
  k_gemm<<<GEMM_GRID, 512, 0, stream>>>(a2, w3T, g2b1, z, NN, 768, 768);
  k_gemm<<<GEMM_GRID, 512, 0, stream>>>(z, w4T, g2b2, h2, NN, 768, 768);

  k_pool1<<<(NN + 31) / 32, 256, 0, stream>>>(h2, batch, sums, cnt);
  k_pool2<<<GG, 64, 0, stream>>>(sums, cnt, dw, db, (float*)d_out);
}